// Round 9
// baseline (48.972 us; speedup 1.0000x reference)
//
#include <hip/hip_runtime.h>
#include <hip/hip_bf16.h>

// FeatureContrast: out[b,i,j,hw] = x[b,c,hw]*exp(w*x[b,c,hw]) / sum_{3x3 ch window}
// over 16x16 channel grid, c=(i+1)*16+(j+1). B=32, HW=4096.
//
// R9: 2-column output strip per thread (4 cs columns, 12 f2 loads, 24 exp).
// Trend confirmed across R2->R8: finer per-thread grain + more waves hides the
// exp-chain VALU overhang above the 237MB-compulsory memory floor (~37.6us).
// full-row 48.8 -> half-row 41.4 -> this. Grid 8 x 98 x 32 = 25088 blocks.

#define NIN 16
#define NOUT 14
#define HW 4096

typedef float f2 __attribute__((ext_vector_type(2)));

__global__ __launch_bounds__(256) void fc_kernel(
    const float* __restrict__ x,
    const float* __restrict__ wp,
    float* __restrict__ out)
{
    const float w = wp[0];
    const int hw2 = (blockIdx.x * blockDim.x + threadIdx.x) * 2;  // 0..4094
    const int iy  = blockIdx.y;        // 0..97: (output row i, strip t)
    const int i   = iy / 7;            // 0..13 (magic-mul)
    const int cb  = (iy % 7) * 2;      // column base: 0,2,..,12
    const int b   = blockIdx.z;        // 0..31

    // Channel rows i..i+2, columns cb..cb+3 (4 cols) feed output row i,
    // output columns cb..cb+1.
    const float* xb = x + ((size_t)(b * (NIN * NIN) + i * NIN + cb)) * HW + hw2;

    f2 cs[4];     // column sums of exp over the 3 channel rows
    f2 num[4];    // x*exp(w*x) of middle row (indices 1,2 used)
    f2 v[4];

    // ---- Row i ----
    #pragma unroll
    for (int c = 0; c < 4; ++c) v[c] = *(const f2*)(xb + (size_t)c * HW);
    #pragma unroll
    for (int c = 0; c < 4; ++c) {
        f2 e; e.x = __expf(v[c].x * w); e.y = __expf(v[c].y * w);
        cs[c] = e;
    }
    // ---- Row i+1 (middle: numerator source) ----
    #pragma unroll
    for (int c = 0; c < 4; ++c) v[c] = *(const f2*)(xb + (size_t)(NIN + c) * HW);
    #pragma unroll
    for (int c = 0; c < 4; ++c) {
        f2 e; e.x = __expf(v[c].x * w); e.y = __expf(v[c].y * w);
        cs[c] += e;
        num[c] = v[c] * e;
    }
    // ---- Row i+2 ----
    #pragma unroll
    for (int c = 0; c < 4; ++c) v[c] = *(const f2*)(xb + (size_t)(2 * NIN + c) * HW);
    #pragma unroll
    for (int c = 0; c < 4; ++c) {
        f2 e; e.x = __expf(v[c].x * w); e.y = __expf(v[c].y * w);
        cs[c] += e;
    }

    // ---- Output: row i, columns cb..cb+1 ----
    float* ob = out + ((size_t)(b * (NOUT * NOUT) + i * NOUT + cb)) * HW + hw2;
    #pragma unroll
    for (int j = 0; j < 2; ++j) {
        f2 s = cs[j] + cs[j + 1] + cs[j + 2];
        f2 d;
        d.x = __fdividef(num[j + 1].x, s.x);
        d.y = __fdividef(num[j + 1].y, s.y);
        *(f2*)(ob + (size_t)j * HW) = d;
    }
}

extern "C" void kernel_launch(void* const* d_in, const int* in_sizes, int n_in,
                              void* d_out, int out_size, void* d_ws, size_t ws_size,
                              hipStream_t stream) {
    const float* x  = (const float*)d_in[0];
    const float* wp = (const float*)d_in[1];
    float* out = (float*)d_out;

    dim3 block(256, 1, 1);
    dim3 grid(HW / (256 * 2), 7 * NOUT, 32);   // 8 x 98 x 32 = 25088 blocks
    hipLaunchKernelGGL(fc_kernel, grid, block, 0, stream, x, wp, out);
}

// Round 10
// 40.532 us; speedup vs baseline: 1.2083x; 1.2083x over previous
//
#include <hip/hip_runtime.h>
#include <hip/hip_bf16.h>

// FeatureContrast: out[b,i,j,hw] = x[b,c,hw]*exp(w*x[b,c,hw]) / sum_{3x3 ch window}
// over 16x16 channel grid, c=(i+1)*16+(j+1). B=32, HW=4096.
//
// R10: exp-exactly-once cooperative block. Block = one b x 32 pixels x ALL 256
// channels. Phase 1: coalesced load of every channel (thread = (col-group,
// pixel-slot), pass = channel row), exp computed ONCE, e -> 32KB LDS; interior
// threads keep num=x*e in registers (static idx). One barrier. Phase 2:
// cols 1..14 build 16 horizontal sums rs[r] from LDS (48 ds_read_b64), then
// roll denom down the 14 output rows register-only. Kills the 3-6x exp/read
// redundancy that R9 showed to be the overhang above the 37.6us memory floor.

#define NIN 16
#define NOUT 14
#define HW 4096
#define PIX 32            // pixels per block
#define SLOTS (PIX / 2)   // 16 f2 slots

typedef float f2 __attribute__((ext_vector_type(2)));

__global__ __launch_bounds__(256) void fc_kernel(
    const float* __restrict__ x,
    const float* __restrict__ wp,
    float* __restrict__ out)
{
    __shared__ f2 elds[NIN * NIN * SLOTS];   // 32 KB: e[ch][slot]

    const float w = wp[0];
    const int tid  = threadIdx.x;
    const int slot = tid & (SLOTS - 1);      // 0..15 (f2 slot)
    const int cg   = tid >> 4;               // 0..15 (channel column)
    const int hw0  = blockIdx.x * PIX;       // 0..4064 step 32
    const int b    = blockIdx.y;             // 0..31

    const float* xb = x + ((size_t)b * (NIN * NIN)) * HW + hw0 + slot * 2;

    f2 num[NIN];   // x*e of channel (p, cg), rows 1..14 used; static-indexed

    // ---- Phase 1: load all 256 channels, one exp each, e -> LDS ----
    #pragma unroll
    for (int p = 0; p < NIN; ++p) {          // channel row (compile-time)
        const int ch = p * NIN + cg;
        f2 v = *(const f2*)(xb + (size_t)ch * HW);
        f2 e;
        e.x = __expf(v.x * w);
        e.y = __expf(v.y * w);
        elds[ch * SLOTS + slot] = e;
        num[p] = v * e;                      // only rows 1..14 consumed
    }

    __syncthreads();

    // ---- Phase 2: cols 1..14 compute outputs ----
    if (cg >= 1 && cg <= NOUT) {
        const int j = cg - 1;                // output column

        // Horizontal 3-sums for all 16 rows at this column
        f2 rs[NIN];
        #pragma unroll
        for (int r = 0; r < NIN; ++r) {
            f2 a = elds[(r * NIN + cg - 1) * SLOTS + slot];
            f2 bb = elds[(r * NIN + cg    ) * SLOTS + slot];
            f2 c = elds[(r * NIN + cg + 1) * SLOTS + slot];
            rs[r] = a + bb + c;
        }

        float* ob = out + ((size_t)b * (NOUT * NOUT) + j) * HW + hw0 + slot * 2;
        #pragma unroll
        for (int i = 0; i < NOUT; ++i) {
            f2 s = rs[i] + rs[i + 1] + rs[i + 2];
            f2 d;
            d.x = __fdividef(num[i + 1].x, s.x);
            d.y = __fdividef(num[i + 1].y, s.y);
            *(f2*)(ob + (size_t)(i * NOUT) * HW) = d;
        }
    }
}

extern "C" void kernel_launch(void* const* d_in, const int* in_sizes, int n_in,
                              void* d_out, int out_size, void* d_ws, size_t ws_size,
                              hipStream_t stream) {
    const float* x  = (const float*)d_in[0];
    const float* wp = (const float*)d_in[1];
    float* out = (float*)d_out;

    dim3 block(256, 1, 1);
    dim3 grid(HW / PIX, 32, 1);   // 128 x 32 = 4096 blocks (16/CU)
    hipLaunchKernelGGL(fc_kernel, grid, block, 0, stream, x, wp, out);
}